// Round 7
// baseline (196.905 us; speedup 1.0000x reference)
//
#include <hip/hip_runtime.h>
#include <stdint.h>

// GAT layer, B=4 N=2048 IN=128 F=64 H=4. adj int32; float tensors are
// bf16 OR fp32 (detected on-device, inline in kc). Pipeline:
//  kc: dtype flag + convert h,W(+transpose),a1,a2 -> bf16; zero fp32 part accum
//  k1: MFMA g = h@W; store g_f in MFMA-B-FRAGMENT order; per (b,h,n): sd, ss,
//      exp pairs e2pn, ssE
//  k2a: read adj once (int4 vec), row sums l -> E1, bitpack adj
//  k2b: fused softmax-numerators + att_mean + PV. QS=16 q-splits, 8192
//      single-wave blocks (~8 waves/SIMD). PV partials via fp32 atomicAdd
//      (16 spread writers/address). History: (256,4) spilled acc; occupancy at
//      4 waves/SIMD left VALUBusy 40% (R6, 56us) -> double in-flight waves.
//  k3: convert part accum -> h_prime

typedef unsigned char u8;
typedef unsigned short u16;
typedef unsigned int u32;
typedef unsigned long long u64;

typedef float f32x4 __attribute__((ext_vector_type(4)));
typedef short s16x8 __attribute__((ext_vector_type(8)));
typedef u32 u32x4 __attribute__((ext_vector_type(4)));

#define B_ 4
#define N_ 2048
#define IN_ 128
#define F_ 64
#define H_ 4
#define QS_ 16
#define PARTN_ (B_ * N_ * F_)

__device__ __forceinline__ float bf2f(u16 b) {
    u32 u = ((u32)b) << 16;
    return __builtin_bit_cast(float, u);
}
__device__ __forceinline__ u16 f2bf(float f) {
    u32 u = __builtin_bit_cast(u32, f);
    u += 0x7FFFu + ((u >> 16) & 1u);  // RNE
    return (u16)(u >> 16);
}
__device__ __forceinline__ u32 pk_bf16(float a, float b) {
#if defined(__has_builtin)
#if __has_builtin(__builtin_amdgcn_cvt_pk_bf16_f32)
    typedef __bf16 bf2_t __attribute__((ext_vector_type(2)));
    bf2_t p = __builtin_amdgcn_cvt_pk_bf16_f32(a, b);
    return __builtin_bit_cast(u32, p);
#else
    return (u32)f2bf(a) | (((u32)f2bf(b)) << 16);
#endif
#else
    return (u32)f2bf(a) | (((u32)f2bf(b)) << 16);
#endif
}

__device__ __forceinline__ u16 conv_elem(const void* p, int i, u32 isbf) {
    if (isbf) return ((const u16*)p)[i];
    return f2bf(((const float*)p)[i]);
}

// ---------------- kc: dtype detect + convert + zero part ----------------
__global__ __launch_bounds__(256) void kc_convert(
    const void* __restrict__ h, const void* __restrict__ W, const void* __restrict__ a1,
    const void* __restrict__ a2, u32* __restrict__ flag, u16* __restrict__ hc,
    u16* __restrict__ wt, u16* __restrict__ a1c, u16* __restrict__ a2c,
    float* __restrict__ partf) {
    __shared__ int cnt[4];
    __shared__ u32 isbf_s;
    int t = threadIdx.x;
    {  // dtype probe on first 256 words of h (identical result per block)
        u32 w = ((const u32*)h)[t];
        int e0 = (int)((w >> 7) & 0xFFu);
        int sane = (e0 >= 100 && e0 <= 145) ? 1 : 0;
#pragma unroll
        for (int m = 1; m < 64; m <<= 1) sane += __shfl_xor(sane, m, 64);
        if ((t & 63) == 0) cnt[t >> 6] = sane;
    }
    __syncthreads();
    if (t == 0) {
        int s = cnt[0] + cnt[1] + cnt[2] + cnt[3];
        isbf_s = (s >= 128) ? 1u : 0u;
        if (blockIdx.x == 0) *flag = isbf_s;
    }
    __syncthreads();
    u32 isbf = isbf_s;

    int idx = blockIdx.x * 256 + t;
    const int NH = B_ * N_ * IN_;
    if (idx < NH) {
        hc[idx] = conv_elem(h, idx, isbf);
        return;
    }
    int j = idx - NH;
    if (j < IN_ * 256) {  // W: [128][256] row-major -> wt[c][k]
        int k = j >> 8, c = j & 255;
        wt[c * IN_ + k] = conv_elem(W, j, isbf);
        return;
    }
    j -= IN_ * 256;
    if (j < F_) {
        a1c[j] = conv_elem(a1, j, isbf);
        return;
    }
    j -= F_;
    if (j < F_) {
        a2c[j] = conv_elem(a2, j, isbf);
        return;
    }
    j -= F_;
    if (j < PARTN_) partf[j] = 0.f;
}

// g_f layout (u16): ((((b*H+h)*4 + ft)*64 + chunk)*64 + quad*16 + l15)*8 + j
//   holds g[f = ft*16+l15][q = chunk*32 + quad*8 + j]  (exact MFMA B-fragment)
__global__ __launch_bounds__(256) void k1_proj(
    const u16* __restrict__ h, const u16* __restrict__ Wt,
    const u16* __restrict__ a1, const u16* __restrict__ a2,
    u16* __restrict__ g_f, u16* __restrict__ sdb, u32* __restrict__ e2pn,
    float* __restrict__ ssA, float2* __restrict__ ssE) {
    int b = blockIdx.x >> 7;
    int n0 = (blockIdx.x & 127) * 16;
    int w = threadIdx.x >> 6;
    int lane = threadIdx.x & 63;
    int quad = lane >> 4, l15 = lane & 15;

    f32x4 acc[4];
#pragma unroll
    for (int i = 0; i < 4; i++) acc[i] = 0.0f;

    s16x8 A[4];
#pragma unroll
    for (int kt = 0; kt < 4; kt++) {
        const s16x8* ap =
            (const s16x8*)(h + ((size_t)(b * N_ + n0 + l15) * IN_ + kt * 32 + quad * 8));
        A[kt] = *ap;
    }
#pragma unroll
    for (int kt = 0; kt < 4; kt++) {
#pragma unroll
        for (int ft = 0; ft < 4; ft++) {
            int c = w * 64 + ft * 16 + l15;
            const s16x8* bp = (const s16x8*)(Wt + ((size_t)c * IN_ + kt * 32 + quad * 8));
            acc[ft] = __builtin_amdgcn_mfma_f32_16x16x32_bf16(A[kt], *bp, acc[ft], 0, 0, 0);
        }
    }
    __shared__ float ct[4][64][20];
#pragma unroll
    for (int ft = 0; ft < 4; ft++)
#pragma unroll
        for (int r = 0; r < 4; r++) ct[w][ft * 16 + l15][quad * 4 + r] = acc[ft][r];
    __syncthreads();

    float v[16];
#pragma unroll
    for (int n = 0; n < 16; n++) v[n] = ct[w][lane][n];

    {  // fragment-order store: block covers quads {gq0, gq0+1} of chunk n0>>5
        int chunk = n0 >> 5;
        int gq0 = (n0 >> 3) & 2;
#pragma unroll
        for (int p = 0; p < 2; p++) {
            int ft = p * 2 + (lane >> 5);
            int lq = (lane >> 4) & 1;
            int fl = lane & 15;
            s16x8 tv;
#pragma unroll
            for (int j = 0; j < 8; j++) tv[j] = (short)f2bf(ct[w][ft * 16 + fl][lq * 8 + j]);
            size_t off =
                ((size_t)(((b * H_ + w) * 4 + ft) * 64 + chunk) * 64 + (gq0 + lq) * 16 + fl) * 8;
            *(s16x8*)(g_f + off) = tv;
        }
    }
    float a1v = bf2f(a1[lane]);
    float a2v = bf2f(a2[lane]);
    float sdv = 0.f, ssv = 0.f;
#pragma unroll
    for (int n = 0; n < 16; n++) {
        float x = v[n] * a1v;
        float y = v[n] * a2v;
#pragma unroll
        for (int m = 1; m < 64; m <<= 1) {
            x += __shfl_xor(x, m, 64);
            y += __shfl_xor(y, m, 64);
        }
        if (lane == n) { sdv = x; ssv = y; }
    }
    if (lane < 16) {
        size_t o = (size_t)(b * H_ + w) * N_ + n0 + lane;
        sdb[o] = f2bf(sdv);
        float e2p = __expf(sdv), e2n = __expf(0.2f * sdv);
        e2pn[o] = (((u32)f2bf(e2p)) << 16) | (u32)f2bf(e2n);
        ssA[o] = ssv;
        ssE[o] = make_float2(__expf(ssv), __expf(0.2f * ssv));
    }
}

// ---------------- k2a: denominators + adj bitpack (vectorized, no ballots) ---
__global__ __launch_bounds__(256) void k2a_rowsum(
    const int* __restrict__ adj, const u16* __restrict__ sdb, const u32* __restrict__ e2pn,
    const float* __restrict__ ssA, const float2* __restrict__ ssE,
    float2* __restrict__ E1, u32* __restrict__ pk32) {
    int b = blockIdx.x >> 9;
    int p0 = (blockIdx.x & 511) * 4;
    int t = threadIdx.x;
    int w = t >> 6, lane = t & 63;

    __shared__ u8 nib[4][512];

    float tau[4][4];
#pragma unroll
    for (int r = 0; r < 4; r++)
#pragma unroll
        for (int hh = 0; hh < 4; hh++)
            tau[r][hh] = -ssA[(size_t)(b * H_ + hh) * N_ + p0 + r];

    float S[32];  // [(r*4+h)*2 + {p,n}]
#pragma unroll
    for (int i = 0; i < 32; i++) S[i] = 0.f;

#pragma unroll
    for (int i = 0; i < 2; i++) {
        int qi = i * 256 + t;
        int q = qi * 4;
        float af[4][4];
#pragma unroll
        for (int r = 0; r < 4; r++) {
            int4 av = *(const int4*)(adj + (size_t)(b * N_ + p0 + r) * N_ + q);
            af[r][0] = (av.x != 0) ? 1.f : 0.f;
            af[r][1] = (av.y != 0) ? 1.f : 0.f;
            af[r][2] = (av.z != 0) ? 1.f : 0.f;
            af[r][3] = (av.w != 0) ? 1.f : 0.f;
            u32 nb = (av.x != 0 ? 1u : 0u) | (av.y != 0 ? 2u : 0u) |
                     (av.z != 0 ? 4u : 0u) | (av.w != 0 ? 8u : 0u);
            nib[r][qi] = (u8)nb;
        }
#pragma unroll
        for (int hh = 0; hh < 4; hh++) {
            size_t o = (size_t)(b * H_ + hh) * N_ + q;
            u64 sd4 = *(const u64*)(sdb + o);
            u32x4 pn4 = *(const u32x4*)(e2pn + o);
            float sdf[4], e2p[4], e2n[4];
#pragma unroll
            for (int j = 0; j < 4; j++) {
                sdf[j] = bf2f((u16)(sd4 >> (16 * j)));
                e2p[j] = __builtin_bit_cast(float, pn4[j] & 0xFFFF0000u);
                e2n[j] = __builtin_bit_cast(float, pn4[j] << 16);
            }
#pragma unroll
            for (int r = 0; r < 4; r++) {
#pragma unroll
                for (int j = 0; j < 4; j++) {
                    bool ge = sdf[j] >= tau[r][hh];
                    S[(r * 4 + hh) * 2 + 0] += ge ? af[r][j] * e2p[j] : 0.f;
                    S[(r * 4 + hh) * 2 + 1] += ge ? 0.f : af[r][j] * e2n[j];
                }
            }
        }
    }
    __syncthreads();
    {
        int r = t >> 6, m8 = t & 63;
        u64 nn = *(const u64*)&nib[r][m8 * 8];
        u32 wd = 0;
#pragma unroll
        for (int d = 0; d < 4; d++) {
            u32 lo = (u32)(nn >> (16 * d)) & 0xFu;
            u32 hi = (u32)(nn >> (16 * d + 8)) & 0xFu;
            wd |= (lo | (hi << 4)) << (8 * d);
        }
        pk32[(size_t)(b * N_ + p0 + r) * 64 + m8] = wd;
    }
#pragma unroll
    for (int k = 0; k < 32; k++) {
        float x = S[k];
#pragma unroll
        for (int m = 1; m < 64; m <<= 1) x += __shfl_xor(x, m, 64);
        S[k] = x;
    }
    __shared__ float sred[4][32];
    if (lane == 0) {
#pragma unroll
        for (int k = 0; k < 32; k++) sred[w][k] = S[k];
    }
    __syncthreads();
    if (t < 16) {
        int r = t >> 2, hh = t & 3;
        float sp = 0.f, sn = 0.f;
#pragma unroll
        for (int ww = 0; ww < 4; ww++) {
            sp += sred[ww][t * 2];
            sn += sred[ww][t * 2 + 1];
        }
        size_t o = (size_t)(b * H_ + hh) * N_ + p0 + r;
        float2 se = ssE[o];
        float l = se.x * sp + se.y * sn;
        float inv = (l > 0.f) ? 0.25f / l : 0.f;  // fold 1/H and 1/l
        E1[o] = make_float2(se.x * inv, se.y * inv);
    }
}

// ---------------- k2b: fused attention + att_mean + PV ----------------
// grid = B * 128 ptiles * 16 qsplits = 8192 single-wave blocks (128 q each).
__global__ __launch_bounds__(64) void k2b_attn(
    const u16* __restrict__ sdb, const u32* __restrict__ e2pn, const float* __restrict__ ssA,
    const float2* __restrict__ E1, const u32* __restrict__ pk32,
    const u16* __restrict__ g_f, const u32* __restrict__ flag, void* __restrict__ d_out_v,
    float* __restrict__ partf) {
    int bid = blockIdx.x;
    int s = bid & (QS_ - 1);
    int pt = (bid >> 4) & 127;
    int b = bid >> 11;
    int qb = s * (N_ / QS_);  // 128 q per block
    int lane = threadIdx.x;   // 0..63
    int quad = lane >> 4, l15 = lane & 15;
    int p0 = pt * 16;
    int row = p0 + l15;
    u32 isbf = *flag;

    __shared__ __align__(8) u16 lsd[4][128];
    __shared__ __align__(8) u32 le2[4][128];
#pragma unroll
    for (int hh = 0; hh < 4; hh++) {
        size_t o = (size_t)(b * H_ + hh) * N_ + qb + lane * 2;
        *(u32*)&lsd[hh][lane * 2] = *(const u32*)(sdb + o);
        *(u64*)&le2[hh][lane * 2] = *(const u64*)(e2pn + o);
    }
    __syncthreads();

    float E1p[4], E1n[4], tau[4];
#pragma unroll
    for (int hh = 0; hh < 4; hh++) {
        size_t o = (size_t)(b * H_ + hh) * N_ + row;
        float2 e1 = E1[o];
        E1p[hh] = e1.x;
        E1n[hh] = e1.y;
        tau[hh] = -ssA[o];
    }
    f32x4 acc[4];  // shared across heads (h' sums over heads)
#pragma unroll
    for (int i = 0; i < 4; i++) acc[i] = 0.0f;

    const u32* pkrow = pk32 + (size_t)(b * N_ + row) * 64 + (qb >> 5);
    u32 pkw[4];
#pragma unroll
    for (int c = 0; c < 4; c++) pkw[c] = pkrow[c];

    const size_t hstride = (size_t)4 * 64 * 512;  // per-head span in u16
    const u16* gb = g_f + (size_t)b * H_ * hstride + (size_t)(qb >> 5) * 512 + lane * 8;

    s16x8 Bc[4], Bn[4];
#pragma unroll
    for (int ft = 0; ft < 4; ft++) Bc[ft] = *(const s16x8*)(gb + (size_t)ft * 32768);

    size_t am_base = ((size_t)(b * N_ + row)) * N_ + qb + quad * 8;
    u16* amb = (u16*)d_out_v + (size_t)B_ * N_ * F_;
    float* amf = (float*)d_out_v + (size_t)B_ * N_ * F_;

#pragma unroll 1
    for (int c = 0; c < 4; c++) {
        int qq = c * 32 + quad * 8;
        u32 byte_ = (pkw[c] >> (quad * 8)) & 0xFFu;
        float bitf[8];
#pragma unroll
        for (int j = 0; j < 8; j++) bitf[j] = ((byte_ >> j) & 1u) ? 1.0f : 0.0f;

        float amv[8];
#pragma unroll
        for (int j = 0; j < 8; j++) amv[j] = 0.f;

#pragma unroll
        for (int hh = 0; hh < 4; hh++) {
            {  // prefetch next (c,hh) stage's B fragments
                int idx = (c * 4 + hh + 1) & 15;
                int c2 = idx >> 2, h2 = idx & 3;
#pragma unroll
                for (int ft = 0; ft < 4; ft++)
                    Bn[ft] = *(const s16x8*)(gb + (size_t)h2 * hstride + (size_t)ft * 32768 +
                                             (size_t)c2 * 512);
            }
            s16x8 sd8 = *(const s16x8*)&lsd[hh][qq];
            u32x4 e2a = *(const u32x4*)&le2[hh][qq];
            u32x4 e2b = *(const u32x4*)&le2[hh][qq + 4];
            float wv[8];
#pragma unroll
            for (int j = 0; j < 8; j++) {
                float sdf = bf2f((u16)sd8[j]);
                bool ge = sdf >= tau[hh];
                u32 pn = (j < 4) ? e2a[j] : e2b[j - 4];
                float e2 = ge ? __builtin_bit_cast(float, pn & 0xFFFF0000u)
                              : __builtin_bit_cast(float, pn << 16);
                float e1v = ge ? E1p[hh] : E1n[hh];
                float ww = e1v * e2 * bitf[j];
                wv[j] = ww;
                amv[j] += ww;
            }
            s16x8 af;
            u32* afp = (u32*)&af;
#pragma unroll
            for (int j = 0; j < 4; j++) afp[j] = pk_bf16(wv[2 * j], wv[2 * j + 1]);
#pragma unroll
            for (int ft = 0; ft < 4; ft++)
                acc[ft] = __builtin_amdgcn_mfma_f32_16x16x32_bf16(af, Bc[ft], acc[ft], 0, 0, 0);
#pragma unroll
            for (int ft = 0; ft < 4; ft++) Bc[ft] = Bn[ft];
        }
        if (isbf) {
            s16x8 amp;
            u32* ampp = (u32*)&amp;
#pragma unroll
            for (int j = 0; j < 4; j++) ampp[j] = pk_bf16(amv[2 * j], amv[2 * j + 1]);
            *(s16x8*)(amb + am_base + c * 32) = amp;
        } else {
            f32x4 lo, hi;
#pragma unroll
            for (int j = 0; j < 4; j++) { lo[j] = amv[j]; hi[j] = amv[j + 4]; }
            *(f32x4*)(amf + am_base + c * 32) = lo;
            *(f32x4*)(amf + am_base + c * 32 + 4) = hi;
        }
    }
#pragma unroll
    for (int ft = 0; ft < 4; ft++) {
#pragma unroll
        for (int r = 0; r < 4; r++) {
            int pout = p0 + quad * 4 + r;
            int f = ft * 16 + l15;
            atomicAdd(&partf[(size_t)(b * N_ + pout) * F_ + f], acc[ft][r]);
        }
    }
}

__global__ __launch_bounds__(256) void k3_reduce(const float* __restrict__ partf,
                                                 const u32* __restrict__ flag,
                                                 void* __restrict__ out) {
    int idx = blockIdx.x * 256 + threadIdx.x;
    float s = partf[idx];
    if (*flag)
        ((u16*)out)[idx] = f2bf(s);
    else
        ((float*)out)[idx] = s;
}

extern "C" void kernel_launch(void* const* d_in, const int* in_sizes, int n_in,
                              void* d_out, int out_size, void* d_ws, size_t ws_size,
                              hipStream_t stream) {
    const void* h = d_in[0];
    const int* adj = (const int*)d_in[1];
    const void* W = d_in[2];
    const void* a1 = d_in[3];
    const void* a2 = d_in[4];

    char* ws = (char*)d_ws;
    u32* flag = (u32*)(ws + 0);
    u16* a1c = (u16*)(ws + 64);
    u16* a2c = (u16*)(ws + 192);
    u16* wt = (u16*)(ws + 1024);
    u16* hc = (u16*)(ws + 66560);
    u16* g_f = (u16*)(ws + 2163712);     // 4 MB, fragment-order
    u16* sdb = (u16*)(ws + 6358016);
    u32* e2pn = (u32*)(ws + 6423552);
    float* ssA = (float*)(ws + 6554624);
    float2* ssE = (float2*)(ws + 6685696);
    float2* E1 = (float2*)(ws + 6947840);
    u32* pk = (u32*)(ws + 7209984);      // 2 MB bitmask
    float* partf = (float*)(ws + 9307136);  // 2 MB fp32 accum, ends ~11.4 MB

    const int KC_TOT = B_ * N_ * IN_ + IN_ * 256 + 2 * F_ + PARTN_;
    kc_convert<<<(KC_TOT + 255) / 256, 256, 0, stream>>>(h, W, a1, a2, flag, hc, wt, a1c,
                                                         a2c, partf);
    k1_proj<<<512, 256, 0, stream>>>(hc, wt, a1c, a2c, g_f, sdb, e2pn, ssA, ssE);
    k2a_rowsum<<<2048, 256, 0, stream>>>(adj, sdb, e2pn, ssA, ssE, E1, pk);
    k2b_attn<<<8192, 64, 0, stream>>>(sdb, e2pn, ssA, E1, (const u32*)pk, g_f, flag,
                                      d_out, partf);
    k3_reduce<<<2048, 256, 0, stream>>>(partf, flag, d_out);
}

// Round 8
// 191.461 us; speedup vs baseline: 1.0284x; 1.0284x over previous
//
#include <hip/hip_runtime.h>
#include <stdint.h>

// GAT layer, B=4 N=2048 IN=128 F=64 H=4. adj int32; float tensors are
// bf16 OR fp32 (detected on-device, inline in kc/k1). Pipeline:
//  kc: dtype flag + convert W(+transpose),a1,a2 -> bf16; zero fp32 part accum
//  k1: MFMA g = h@W (h converted inline); store g_f in MFMA-B-FRAGMENT order;
//      sd/ss dots via LDS-redistributed fp32 sums (1 shuffle, not 192)
//  k2a: read adj once (int4 vec), row sums l -> E1, bitpack adj
//  k2b: fused softmax-numerators + att_mean + PV. QS=16 q-splits, 8192
//      single-wave blocks. PV partials via fp32 atomicAdd. History: occupancy
//      knobs don't move it (resident waves pinned ~8/CU); only critical-path
//      cuts help (75->56->53). unroll 2 on c-loop for cross-iter ILP.
//  k3: convert part accum -> h_prime

typedef unsigned char u8;
typedef unsigned short u16;
typedef unsigned int u32;
typedef unsigned long long u64;

typedef float f32x4 __attribute__((ext_vector_type(4)));
typedef short s16x8 __attribute__((ext_vector_type(8)));
typedef u32 u32x4 __attribute__((ext_vector_type(4)));

#define B_ 4
#define N_ 2048
#define IN_ 128
#define F_ 64
#define H_ 4
#define QS_ 16
#define PARTN_ (B_ * N_ * F_)

__device__ __forceinline__ float bf2f(u16 b) {
    u32 u = ((u32)b) << 16;
    return __builtin_bit_cast(float, u);
}
__device__ __forceinline__ u16 f2bf(float f) {
    u32 u = __builtin_bit_cast(u32, f);
    u += 0x7FFFu + ((u >> 16) & 1u);  // RNE
    return (u16)(u >> 16);
}
__device__ __forceinline__ u32 pk_bf16(float a, float b) {
#if defined(__has_builtin)
#if __has_builtin(__builtin_amdgcn_cvt_pk_bf16_f32)
    typedef __bf16 bf2_t __attribute__((ext_vector_type(2)));
    bf2_t p = __builtin_amdgcn_cvt_pk_bf16_f32(a, b);
    return __builtin_bit_cast(u32, p);
#else
    return (u32)f2bf(a) | (((u32)f2bf(b)) << 16);
#endif
#else
    return (u32)f2bf(a) | (((u32)f2bf(b)) << 16);
#endif
}

__device__ __forceinline__ u16 conv_elem(const void* p, int i, u32 isbf) {
    if (isbf) return ((const u16*)p)[i];
    return f2bf(((const float*)p)[i]);
}

// ---------------- kc: dtype detect + convert W/a1/a2 + zero part ----------------
__global__ __launch_bounds__(256) void kc_convert(
    const void* __restrict__ h, const void* __restrict__ W, const void* __restrict__ a1,
    const void* __restrict__ a2, u32* __restrict__ flag, u16* __restrict__ wt,
    u16* __restrict__ a1c, u16* __restrict__ a2c, float* __restrict__ partf) {
    __shared__ int cnt[4];
    __shared__ u32 isbf_s;
    int t = threadIdx.x;
    {  // dtype probe on first 256 words of h (identical result per block)
        u32 w = ((const u32*)h)[t];
        int e0 = (int)((w >> 7) & 0xFFu);
        int sane = (e0 >= 100 && e0 <= 145) ? 1 : 0;
#pragma unroll
        for (int m = 1; m < 64; m <<= 1) sane += __shfl_xor(sane, m, 64);
        if ((t & 63) == 0) cnt[t >> 6] = sane;
    }
    __syncthreads();
    if (t == 0) {
        int s = cnt[0] + cnt[1] + cnt[2] + cnt[3];
        isbf_s = (s >= 128) ? 1u : 0u;
        if (blockIdx.x == 0) *flag = isbf_s;
    }
    __syncthreads();
    u32 isbf = isbf_s;

    int j = blockIdx.x * 256 + t;
    if (j < IN_ * 256) {  // W: [128][256] row-major -> wt[c][k]
        int k = j >> 8, c = j & 255;
        wt[c * IN_ + k] = conv_elem(W, j, isbf);
        return;
    }
    j -= IN_ * 256;
    if (j < F_) {
        a1c[j] = conv_elem(a1, j, isbf);
        return;
    }
    j -= F_;
    if (j < F_) {
        a2c[j] = conv_elem(a2, j, isbf);
        return;
    }
    j -= F_;
    if (j < PARTN_) partf[j] = 0.f;
}

// g_f layout (u16): ((((b*H+h)*4 + ft)*64 + chunk)*64 + quad*16 + l15)*8 + j
//   holds g[f = ft*16+l15][q = chunk*32 + quad*8 + j]  (exact MFMA B-fragment)
__global__ __launch_bounds__(256) void k1_proj(
    const void* __restrict__ hraw, const u32* __restrict__ flag, const u16* __restrict__ Wt,
    const u16* __restrict__ a1, const u16* __restrict__ a2,
    u16* __restrict__ g_f, u16* __restrict__ sdb, u32* __restrict__ e2pn,
    float* __restrict__ ssA, float2* __restrict__ ssE) {
    int b = blockIdx.x >> 7;
    int n0 = (blockIdx.x & 127) * 16;
    int w = threadIdx.x >> 6;
    int lane = threadIdx.x & 63;
    int quad = lane >> 4, l15 = lane & 15;
    u32 isbf = *flag;

    f32x4 acc[4];
#pragma unroll
    for (int i = 0; i < 4; i++) acc[i] = 0.0f;

    s16x8 A[4];
    if (isbf) {
        const u16* hb = (const u16*)hraw;
#pragma unroll
        for (int kt = 0; kt < 4; kt++)
            A[kt] = *(const s16x8*)(hb + ((size_t)(b * N_ + n0 + l15) * IN_ + kt * 32 + quad * 8));
    } else {
        const float* hf = (const float*)hraw;
#pragma unroll
        for (int kt = 0; kt < 4; kt++) {
            size_t o = (size_t)(b * N_ + n0 + l15) * IN_ + kt * 32 + quad * 8;
            f32x4 lo = *(const f32x4*)(hf + o);
            f32x4 hi = *(const f32x4*)(hf + o + 4);
            u32* ap = (u32*)&A[kt];
            ap[0] = pk_bf16(lo[0], lo[1]);
            ap[1] = pk_bf16(lo[2], lo[3]);
            ap[2] = pk_bf16(hi[0], hi[1]);
            ap[3] = pk_bf16(hi[2], hi[3]);
        }
    }
#pragma unroll
    for (int kt = 0; kt < 4; kt++) {
#pragma unroll
        for (int ft = 0; ft < 4; ft++) {
            int c = w * 64 + ft * 16 + l15;
            const s16x8* bp = (const s16x8*)(Wt + ((size_t)c * IN_ + kt * 32 + quad * 8));
            acc[ft] = __builtin_amdgcn_mfma_f32_16x16x32_bf16(A[kt], *bp, acc[ft], 0, 0, 0);
        }
    }
    __shared__ float ct[4][64][20];  // [wave][f][n]
#pragma unroll
    for (int ft = 0; ft < 4; ft++)
#pragma unroll
        for (int r = 0; r < 4; r++) ct[w][ft * 16 + l15][quad * 4 + r] = acc[ft][r];
    __syncthreads();

    {  // fragment-order store: block covers quads {gq0, gq0+1} of chunk n0>>5
        int chunk = n0 >> 5;
        int gq0 = (n0 >> 3) & 2;
#pragma unroll
        for (int p = 0; p < 2; p++) {
            int ft = p * 2 + (lane >> 5);
            int lq = (lane >> 4) & 1;
            int fl = lane & 15;
            s16x8 tv;
#pragma unroll
            for (int j = 0; j < 8; j++) tv[j] = (short)f2bf(ct[w][ft * 16 + fl][lq * 8 + j]);
            size_t off =
                ((size_t)(((b * H_ + w) * 4 + ft) * 64 + chunk) * 64 + (gq0 + lq) * 16 + fl) * 8;
            *(s16x8*)(g_f + off) = tv;
        }
    }
    // sd/ss dots: lane -> (n = lane&15, vec = (lane>>4)&1, half = lane>>5)
    {
        int dn = lane & 15;
        int dvec = (lane >> 4) & 1;
        int dhalf = lane >> 5;
        const u16* av = dvec ? a2 : a1;
        float x = 0.f;
#pragma unroll
        for (int i = 0; i < 32; i++) {
            int f = dhalf * 32 + i;
            x += ct[w][f][dn] * bf2f(av[f]);
        }
        x += __shfl_xor(x, 32, 64);
        if (lane < 32) {
            size_t o = (size_t)(b * H_ + w) * N_ + n0 + dn;
            if (dvec == 0) {
                sdb[o] = f2bf(x);
                float e2p = __expf(x), e2n = __expf(0.2f * x);
                e2pn[o] = (((u32)f2bf(e2p)) << 16) | (u32)f2bf(e2n);
            } else {
                ssA[o] = x;
                ssE[o] = make_float2(__expf(x), __expf(0.2f * x));
            }
        }
    }
}

// ---------------- k2a: denominators + adj bitpack (vectorized, no ballots) ---
__global__ __launch_bounds__(256) void k2a_rowsum(
    const int* __restrict__ adj, const u16* __restrict__ sdb, const u32* __restrict__ e2pn,
    const float* __restrict__ ssA, const float2* __restrict__ ssE,
    float2* __restrict__ E1, u32* __restrict__ pk32) {
    int b = blockIdx.x >> 9;
    int p0 = (blockIdx.x & 511) * 4;
    int t = threadIdx.x;
    int w = t >> 6, lane = t & 63;

    __shared__ u8 nib[4][512];

    float tau[4][4];
#pragma unroll
    for (int r = 0; r < 4; r++)
#pragma unroll
        for (int hh = 0; hh < 4; hh++)
            tau[r][hh] = -ssA[(size_t)(b * H_ + hh) * N_ + p0 + r];

    float S[32];  // [(r*4+h)*2 + {p,n}]
#pragma unroll
    for (int i = 0; i < 32; i++) S[i] = 0.f;

#pragma unroll
    for (int i = 0; i < 2; i++) {
        int qi = i * 256 + t;
        int q = qi * 4;
        float af[4][4];
#pragma unroll
        for (int r = 0; r < 4; r++) {
            int4 av = *(const int4*)(adj + (size_t)(b * N_ + p0 + r) * N_ + q);
            af[r][0] = (av.x != 0) ? 1.f : 0.f;
            af[r][1] = (av.y != 0) ? 1.f : 0.f;
            af[r][2] = (av.z != 0) ? 1.f : 0.f;
            af[r][3] = (av.w != 0) ? 1.f : 0.f;
            u32 nb = (av.x != 0 ? 1u : 0u) | (av.y != 0 ? 2u : 0u) |
                     (av.z != 0 ? 4u : 0u) | (av.w != 0 ? 8u : 0u);
            nib[r][qi] = (u8)nb;
        }
#pragma unroll
        for (int hh = 0; hh < 4; hh++) {
            size_t o = (size_t)(b * H_ + hh) * N_ + q;
            u64 sd4 = *(const u64*)(sdb + o);
            u32x4 pn4 = *(const u32x4*)(e2pn + o);
            float sdf[4], e2p[4], e2n[4];
#pragma unroll
            for (int j = 0; j < 4; j++) {
                sdf[j] = bf2f((u16)(sd4 >> (16 * j)));
                e2p[j] = __builtin_bit_cast(float, pn4[j] & 0xFFFF0000u);
                e2n[j] = __builtin_bit_cast(float, pn4[j] << 16);
            }
#pragma unroll
            for (int r = 0; r < 4; r++) {
#pragma unroll
                for (int j = 0; j < 4; j++) {
                    bool ge = sdf[j] >= tau[r][hh];
                    S[(r * 4 + hh) * 2 + 0] += ge ? af[r][j] * e2p[j] : 0.f;
                    S[(r * 4 + hh) * 2 + 1] += ge ? 0.f : af[r][j] * e2n[j];
                }
            }
        }
    }
    __syncthreads();
    {
        int r = t >> 6, m8 = t & 63;
        u64 nn = *(const u64*)&nib[r][m8 * 8];
        u32 wd = 0;
#pragma unroll
        for (int d = 0; d < 4; d++) {
            u32 lo = (u32)(nn >> (16 * d)) & 0xFu;
            u32 hi = (u32)(nn >> (16 * d + 8)) & 0xFu;
            wd |= (lo | (hi << 4)) << (8 * d);
        }
        pk32[(size_t)(b * N_ + p0 + r) * 64 + m8] = wd;
    }
#pragma unroll
    for (int k = 0; k < 32; k++) {
        float x = S[k];
#pragma unroll
        for (int m = 1; m < 64; m <<= 1) x += __shfl_xor(x, m, 64);
        S[k] = x;
    }
    __shared__ float sred[4][32];
    if (lane == 0) {
#pragma unroll
        for (int k = 0; k < 32; k++) sred[w][k] = S[k];
    }
    __syncthreads();
    if (t < 16) {
        int r = t >> 2, hh = t & 3;
        float sp = 0.f, sn = 0.f;
#pragma unroll
        for (int ww = 0; ww < 4; ww++) {
            sp += sred[ww][t * 2];
            sn += sred[ww][t * 2 + 1];
        }
        size_t o = (size_t)(b * H_ + hh) * N_ + p0 + r;
        float2 se = ssE[o];
        float l = se.x * sp + se.y * sn;
        float inv = (l > 0.f) ? 0.25f / l : 0.f;  // fold 1/H and 1/l
        E1[o] = make_float2(se.x * inv, se.y * inv);
    }
}

// ---------------- k2b: fused attention + att_mean + PV ----------------
// grid = B * 128 ptiles * 16 qsplits = 8192 single-wave blocks (128 q each).
__global__ __launch_bounds__(64) void k2b_attn(
    const u16* __restrict__ sdb, const u32* __restrict__ e2pn, const float* __restrict__ ssA,
    const float2* __restrict__ E1, const u32* __restrict__ pk32,
    const u16* __restrict__ g_f, const u32* __restrict__ flag, void* __restrict__ d_out_v,
    float* __restrict__ partf) {
    int bid = blockIdx.x;
    int s = bid & (QS_ - 1);
    int pt = (bid >> 4) & 127;
    int b = bid >> 11;
    int qb = s * (N_ / QS_);  // 128 q per block
    int lane = threadIdx.x;   // 0..63
    int quad = lane >> 4, l15 = lane & 15;
    int p0 = pt * 16;
    int row = p0 + l15;
    u32 isbf = *flag;

    __shared__ __align__(8) u16 lsd[4][128];
    __shared__ __align__(8) u32 le2[4][128];
#pragma unroll
    for (int hh = 0; hh < 4; hh++) {
        size_t o = (size_t)(b * H_ + hh) * N_ + qb + lane * 2;
        *(u32*)&lsd[hh][lane * 2] = *(const u32*)(sdb + o);
        *(u64*)&le2[hh][lane * 2] = *(const u64*)(e2pn + o);
    }
    __syncthreads();

    float E1p[4], E1n[4], tau[4];
#pragma unroll
    for (int hh = 0; hh < 4; hh++) {
        size_t o = (size_t)(b * H_ + hh) * N_ + row;
        float2 e1 = E1[o];
        E1p[hh] = e1.x;
        E1n[hh] = e1.y;
        tau[hh] = -ssA[o];
    }
    f32x4 acc[4];  // shared across heads (h' sums over heads)
#pragma unroll
    for (int i = 0; i < 4; i++) acc[i] = 0.0f;

    const u32* pkrow = pk32 + (size_t)(b * N_ + row) * 64 + (qb >> 5);
    u32 pkw[4];
#pragma unroll
    for (int c = 0; c < 4; c++) pkw[c] = pkrow[c];

    const size_t hstride = (size_t)4 * 64 * 512;  // per-head span in u16
    const u16* gb = g_f + (size_t)b * H_ * hstride + (size_t)(qb >> 5) * 512 + lane * 8;

    s16x8 Bc[4], Bn[4];
#pragma unroll
    for (int ft = 0; ft < 4; ft++) Bc[ft] = *(const s16x8*)(gb + (size_t)ft * 32768);

    size_t am_base = ((size_t)(b * N_ + row)) * N_ + qb + quad * 8;
    u16* amb = (u16*)d_out_v + (size_t)B_ * N_ * F_;
    float* amf = (float*)d_out_v + (size_t)B_ * N_ * F_;

#pragma unroll 2
    for (int c = 0; c < 4; c++) {
        int qq = c * 32 + quad * 8;
        u32 byte_ = (pkw[c] >> (quad * 8)) & 0xFFu;
        float bitf[8];
#pragma unroll
        for (int j = 0; j < 8; j++) bitf[j] = ((byte_ >> j) & 1u) ? 1.0f : 0.0f;

        float amv[8];
#pragma unroll
        for (int j = 0; j < 8; j++) amv[j] = 0.f;

#pragma unroll
        for (int hh = 0; hh < 4; hh++) {
            {  // prefetch next (c,hh) stage's B fragments
                int idx = (c * 4 + hh + 1) & 15;
                int c2 = idx >> 2, h2 = idx & 3;
#pragma unroll
                for (int ft = 0; ft < 4; ft++)
                    Bn[ft] = *(const s16x8*)(gb + (size_t)h2 * hstride + (size_t)ft * 32768 +
                                             (size_t)c2 * 512);
            }
            s16x8 sd8 = *(const s16x8*)&lsd[hh][qq];
            u32x4 e2a = *(const u32x4*)&le2[hh][qq];
            u32x4 e2b = *(const u32x4*)&le2[hh][qq + 4];
            float wv[8];
#pragma unroll
            for (int j = 0; j < 8; j++) {
                float sdf = bf2f((u16)sd8[j]);
                bool ge = sdf >= tau[hh];
                u32 pn = (j < 4) ? e2a[j] : e2b[j - 4];
                float e2 = ge ? __builtin_bit_cast(float, pn & 0xFFFF0000u)
                              : __builtin_bit_cast(float, pn << 16);
                float e1v = ge ? E1p[hh] : E1n[hh];
                float ww = e1v * e2 * bitf[j];
                wv[j] = ww;
                amv[j] += ww;
            }
            s16x8 af;
            u32* afp = (u32*)&af;
#pragma unroll
            for (int j = 0; j < 4; j++) afp[j] = pk_bf16(wv[2 * j], wv[2 * j + 1]);
#pragma unroll
            for (int ft = 0; ft < 4; ft++)
                acc[ft] = __builtin_amdgcn_mfma_f32_16x16x32_bf16(af, Bc[ft], acc[ft], 0, 0, 0);
#pragma unroll
            for (int ft = 0; ft < 4; ft++) Bc[ft] = Bn[ft];
        }
        if (isbf) {
            s16x8 amp;
            u32* ampp = (u32*)&amp;
#pragma unroll
            for (int j = 0; j < 4; j++) ampp[j] = pk_bf16(amv[2 * j], amv[2 * j + 1]);
            *(s16x8*)(amb + am_base + c * 32) = amp;
        } else {
            f32x4 lo, hi;
#pragma unroll
            for (int j = 0; j < 4; j++) { lo[j] = amv[j]; hi[j] = amv[j + 4]; }
            *(f32x4*)(amf + am_base + c * 32) = lo;
            *(f32x4*)(amf + am_base + c * 32 + 4) = hi;
        }
    }
#pragma unroll
    for (int ft = 0; ft < 4; ft++) {
#pragma unroll
        for (int r = 0; r < 4; r++) {
            int pout = p0 + quad * 4 + r;
            int f = ft * 16 + l15;
            atomicAdd(&partf[(size_t)(b * N_ + pout) * F_ + f], acc[ft][r]);
        }
    }
}

__global__ __launch_bounds__(256) void k3_reduce(const float* __restrict__ partf,
                                                 const u32* __restrict__ flag,
                                                 void* __restrict__ out) {
    int idx = blockIdx.x * 256 + threadIdx.x;
    float s = partf[idx];
    if (*flag)
        ((u16*)out)[idx] = f2bf(s);
    else
        ((float*)out)[idx] = s;
}

extern "C" void kernel_launch(void* const* d_in, const int* in_sizes, int n_in,
                              void* d_out, int out_size, void* d_ws, size_t ws_size,
                              hipStream_t stream) {
    const void* h = d_in[0];
    const int* adj = (const int*)d_in[1];
    const void* W = d_in[2];
    const void* a1 = d_in[3];
    const void* a2 = d_in[4];

    char* ws = (char*)d_ws;
    u32* flag = (u32*)(ws + 0);
    u16* a1c = (u16*)(ws + 64);
    u16* a2c = (u16*)(ws + 192);
    u16* wt = (u16*)(ws + 1024);           //  64 KB, ends 66560
    u16* g_f = (u16*)(ws + 66560);         //   4 MB, ends 4260864
    u16* sdb = (u16*)(ws + 4260864);       //  64 KB, ends 4326400
    u32* e2pn = (u32*)(ws + 4326400);      // 128 KB, ends 4457472
    float* ssA = (float*)(ws + 4457472);   // 128 KB, ends 4588544
    float2* ssE = (float2*)(ws + 4588544); // 256 KB, ends 4850688
    float2* E1 = (float2*)(ws + 4850688);  // 256 KB, ends 5112832
    u32* pk = (u32*)(ws + 5112832);        //   2 MB, ends 7209984
    float* partf = (float*)(ws + 7209984); //   2 MB, ends 9307136 (~9.3 MB)

    const int KC_TOT = IN_ * 256 + 2 * F_ + PARTN_;
    kc_convert<<<(KC_TOT + 255) / 256, 256, 0, stream>>>(h, W, a1, a2, flag, wt, a1c, a2c,
                                                         partf);
    k1_proj<<<512, 256, 0, stream>>>(h, flag, wt, a1c, a2c, g_f, sdb, e2pn, ssA, ssE);
    k2a_rowsum<<<2048, 256, 0, stream>>>(adj, sdb, e2pn, ssA, ssE, E1, pk);
    k2b_attn<<<8192, 64, 0, stream>>>(sdb, e2pn, ssA, E1, (const u32*)pk, g_f, flag,
                                      d_out, partf);
    k3_reduce<<<2048, 256, 0, stream>>>(partf, flag, d_out);
}